// Round 12
// baseline (461.525 us; speedup 1.0000x reference)
//
#include <hip/hip_runtime.h>
#include <math.h>

// ---------------------------------------------------------------------------
// GATv2 x3 + global_mean_pool + MLP, MI355X (gfx950).
// R30: GEMM LDS diet, done right. R28 failed because direct B loads were
// consumed same-iteration (exposed L2 latency). Now Bh is prefetched into
// REGISTERS one full iteration ahead (same pipeline distance as the DMA
// stages; drained by the same pre-barrier vmcnt(0)), via unroll-by-2
// ping-pong (named bhA/bhB, no runtime indexing). A and Bl stay
// global_load_lds-staged. LDS 48KB -> 34KB (loop 2x16KB; epilogue sC 33.8KB
// is the max) -> 4 blocks/CU by LDS; VGPR ~112 keeps 4 waves/SIMD.
// B read at col ks+q*8 is bit-identical (swizzle pair cancels; verified in
// R28's passing run). Everything else unchanged from R29.
// ---------------------------------------------------------------------------

typedef __attribute__((ext_vector_type(4))) float f32x4;
typedef __attribute__((ext_vector_type(8))) _Float16 f16x8;
typedef __attribute__((ext_vector_type(4))) _Float16 f16x4;
typedef __attribute__((ext_vector_type(2))) _Float16 f16x2;

__device__ __forceinline__ float elu1(float x) {
    return (x > 0.f) ? x : (__expf(x) - 1.f);
}
// packed leaky: max(s, 0.2*s) elementwise (valid for slope<1)
__device__ __forceinline__ f16x2 pk_leaky(f16x2 s) {
    const f16x2 slope = {(_Float16)0.2f, (_Float16)0.2f};
    return __builtin_elementwise_max(s, s * slope);
}

// 16-lane row sum via DPP mov (compiler-managed hazards).
__device__ __forceinline__ float dpp_sum16(float v) {
    int t;
    t = __builtin_amdgcn_mov_dpp(__float_as_int(v), 0xB1, 0xF, 0xF, true);
    v += __int_as_float(t);
    t = __builtin_amdgcn_mov_dpp(__float_as_int(v), 0x4E, 0xF, 0xF, true);
    v += __int_as_float(t);
    t = __builtin_amdgcn_mov_dpp(__float_as_int(v), 0x141, 0xF, 0xF, true);
    v += __int_as_float(t);
    t = __builtin_amdgcn_mov_dpp(__float_as_int(v), 0x140, 0xF, 0xF, true);
    v += __int_as_float(t);
    return v;
}

// ------------------------------ CSR build ---------------------------------
// 3-phase scan. S1: chunk sums (256 elems/chunk).
__global__ __launch_bounds__(256) void scan1_kernel(const int* __restrict__ cnt,
                                                    int* __restrict__ psum, int N) {
    __shared__ int red[256];
    int idx = blockIdx.x * 256 + threadIdx.x;
    red[threadIdx.x] = (idx < N) ? cnt[idx] : 0;
    __syncthreads();
    for (int s = 128; s > 0; s >>= 1) {
        if (threadIdx.x < s) red[threadIdx.x] += red[threadIdx.x + s];
        __syncthreads();
    }
    if (threadIdx.x == 0) psum[blockIdx.x] = red[0];
}
// S2: exclusive scan of nch partials — 128-wide Hillis-Steele (nch <= 128).
__global__ __launch_bounds__(128) void scan2_kernel(int* __restrict__ psum, int nch) {
    __shared__ int buf[128];
    int t = threadIdx.x;
    int v = (t < nch) ? psum[t] : 0;
    buf[t] = v;
    __syncthreads();
    for (int off = 1; off < 128; off <<= 1) {
        int x = (t >= off) ? buf[t - off] : 0;
        __syncthreads();
        buf[t] += x;
        __syncthreads();
    }
    if (t < nch) psum[t] = buf[t] - v;   // exclusive
}
// S3: per-chunk inclusive scan (coalesced) + chunk offset -> rowstart/cursor.
__global__ __launch_bounds__(256) void scan3_kernel(const int* __restrict__ cnt,
                                                    const int* __restrict__ psum,
                                                    int* __restrict__ rowstart,
                                                    int* __restrict__ cursor, int N) {
    __shared__ int buf[256];
    int idx = blockIdx.x * 256 + threadIdx.x;
    int v = (idx < N) ? cnt[idx] : 0;
    buf[threadIdx.x] = v;
    __syncthreads();
    for (int off = 1; off < 256; off <<= 1) {
        int t = (threadIdx.x >= off) ? buf[threadIdx.x - off] : 0;
        __syncthreads();
        buf[threadIdx.x] += t;
        __syncthreads();
    }
    int excl = buf[threadIdx.x] - v + psum[blockIdx.x];
    if (idx < N) {
        rowstart[idx] = excl;
        cursor[idx]   = excl;
        if (idx == N - 1) rowstart[N] = excl + v;
    }
}

__global__ void scatter_kernel(const int* __restrict__ src, const int* __restrict__ dst,
                               int* __restrict__ cursor, int* __restrict__ csr_src,
                               int E, int N) {
    int e = blockIdx.x * 256 + threadIdx.x;
    if (e < E + N) {
        int d, s;
        if (e < E) { d = dst[e]; s = src[e]; }
        else       { d = e - E; s = e - E; }
        int pos = atomicAdd(&cursor[d], 1);
        csr_src[pos] = s;
    }
}

// ------- fused prep: convWT x3 + convA + boundary + degree count -----------
// All roles are mutually independent; dispatched by blockIdx.x range.
__device__ __forceinline__ void convWT_body(
    const float* __restrict__ Wl, const float* __restrict__ Wr,
    _Float16* __restrict__ Bth, _Float16* __restrict__ Btl,
    int K, int Nh, int bx, int by, int t) {
    __shared__ float tile[32][33];
    int kb = bx * 32;
    int nb = by * 32;
    int tx = t & 31;
    int ty = t >> 5;     // 0..7
#pragma unroll
    for (int j = 0; j < 4; ++j) {
        int kk = kb + ty + j * 8;
        int nn = nb + tx;
        float v = (nn < Nh) ? Wl[(size_t)kk * Nh + nn]
                            : Wr[(size_t)kk * Nh + (nn - Nh)];
        tile[ty + j * 8][tx] = v;
    }
    __syncthreads();
#pragma unroll
    for (int j = 0; j < 4; ++j) {
        int nn = nb + ty + j * 8;
        int kk = kb + tx;
        float v = tile[tx][ty + j * 8];
        _Float16 h = (_Float16)v;
        Bth[(size_t)nn * K + kk] = h;
        Btl[(size_t)nn * K + kk] = (_Float16)(v - (float)h);
    }
}

__global__ __launch_bounds__(256) void prep_kernel(
    const float* __restrict__ Wl1, const float* __restrict__ Wr1,
    _Float16* __restrict__ Wth1, _Float16* __restrict__ Wtl1,
    const float* __restrict__ Wl2, const float* __restrict__ Wr2,
    _Float16* __restrict__ Wth2, _Float16* __restrict__ Wtl2,
    const float* __restrict__ Wl3, const float* __restrict__ Wr3,
    _Float16* __restrict__ Wth3, _Float16* __restrict__ Wtl3,
    const float* __restrict__ X, _Float16* __restrict__ A,
    int n_valid, int n_total,
    const int* __restrict__ batch, int* __restrict__ gstart, int N, int B,
    const int* __restrict__ edst, int* __restrict__ cnt, int E) {
    int b = blockIdx.x;
    int t = threadIdx.x;
    if (b < 128) {                       // convWT1: K=128, Nh=512
        convWT_body(Wl1, Wr1, Wth1, Wtl1, 128, 512, b & 3, b >> 2, t);
    } else if (b < 640) {                // convWT2: K=512, Nh=512
        int l = b - 128;
        convWT_body(Wl2, Wr2, Wth2, Wtl2, 512, 512, l & 15, l >> 4, t);
    } else if (b < 768) {                // convWT3: K=512, Nh=128
        int l = b - 640;
        convWT_body(Wl3, Wr3, Wth3, Wtl3, 512, 128, l & 15, l >> 4, t);
    } else if (b < 3328) {               // convA: fp32 -> fp16, 4 elems/thread
        int i = ((b - 768) * 256 + t) * 4;
        if (i < n_total) {
            float4 v = (i < n_valid) ? *(const float4*)(X + i)
                                     : make_float4(0.f, 0.f, 0.f, 0.f);
            f16x4 h;
            h.x = (_Float16)v.x; h.y = (_Float16)v.y;
            h.z = (_Float16)v.z; h.w = (_Float16)v.w;
            *(f16x4*)(A + i) = h;
        }
    } else if (b < 3407) {               // boundary: gstart from sorted batch
        int n = (b - 3328) * 256 + t;
        if (n > N) return;
        int cur  = (n < N) ? batch[n] : B;
        int prev = (n == 0) ? -1 : batch[n - 1];
        for (int g = prev + 1; g <= cur; ++g) gstart[g] = n;
    } else {                             // count: degree histogram (+selfloop)
        int e = (b - 3407) * 256 + t;
        if (e < E + N) {
            int d = (e < E) ? edst[e] : (e - E);
            atomicAdd(&cnt[d], 1);
        }
    }
}

// --------------------------- f16 2-product MFMA GEMM -----------------------
// Logical C[Mp x 2Nh] = A x B + bias; left half -> P, right half -> Q (fp16).
// A and Bl staged via global_load_lds (double-buffered, XOR-swizzled, 2x16KB);
// Bh prefetched into registers one iteration ahead (ping-pong bhA/bhB).
// Direct Bh read at col ks+q*8 is bit-identical (swizzle pair cancels).
#define SCW 132   // epilogue LDS row stride (f32)
__global__ __launch_bounds__(256, 1) void gemm_f16_kernel(
    const _Float16* __restrict__ A,
    const _Float16* __restrict__ Bh, const _Float16* __restrict__ Bl,
    const float* __restrict__ biasL, const float* __restrict__ biasR, int Nh_,
    _Float16* __restrict__ P, _Float16* __restrict__ Q, int K, int NT) {
    __shared__ __align__(16) char smem[34816];  // loop: 2x16KB; epi: sC 33.8KB
    float* sC = (float*)(smem);

    const int tid  = threadIdx.x;
    const int lane = tid & 63;
    const int wv   = tid >> 6;
    const int wm   = wv & 1;
    const int wn   = wv >> 1;
    const int fm   = lane & 15;
    const int q    = lane >> 4;
    const int qa   = q ^ ((fm >> 1) & 3);   // swizzled read slot

    const int bi = blockIdx.x;
    const int kx = bi & 7;
    const int tt = bi >> 3;
    const int m0 = ((tt / NT) * 8 + kx) * 128;
    const int n0 = (tt % NT) * 128;

    const int r0  = lane >> 2;
    // swizzled per-lane source k-offset: slot_src = (lane&3) ^ ((lane>>3)&3)
    const int kcs = (((lane & 3) ^ ((lane >> 3) & 3)) << 3);

    f32x4 acc[4][4];
#pragma unroll
    for (int i = 0; i < 4; ++i)
#pragma unroll
        for (int j = 0; j < 4; ++j) {
            acc[i][j].x = 0.f; acc[i][j].y = 0.f;
            acc[i][j].z = 0.f; acc[i][j].w = 0.f;
        }

    const int nIters = K >> 5;   // always even (K=128 or 512)
    const int brow = n0 + wn * 64 + fm;

    // stage A/Bl for it=0 into buffer 0
    {
        char* base = smem;
#pragma unroll
        for (int j = 0; j < 2; ++j) {
            int wc  = wv * 2 + j;
            int row = wc * 16 + r0;
            size_t ga = (size_t)(m0 + row) * K + kcs;
            size_t gb = (size_t)(n0 + row) * K + kcs;
            int lofs = wc * 1024;
            __builtin_amdgcn_global_load_lds(
                (const __attribute__((address_space(1))) void*)(A + ga),
                (__attribute__((address_space(3))) void*)(base + lofs), 16, 0, 0);
            __builtin_amdgcn_global_load_lds(
                (const __attribute__((address_space(1))) void*)(Bl + gb),
                (__attribute__((address_space(3))) void*)(base + 8192 + lofs), 16, 0, 0);
        }
    }
    // Bh registers for it=0
    f16x8 bhA0, bhA1, bhA2, bhA3, bhB0, bhB1, bhB2, bhB3;
    bhA0 = *(const f16x8*)(Bh + (size_t)(brow)      * K + q * 8);
    bhA1 = *(const f16x8*)(Bh + (size_t)(brow + 16) * K + q * 8);
    bhA2 = *(const f16x8*)(Bh + (size_t)(brow + 32) * K + q * 8);
    bhA3 = *(const f16x8*)(Bh + (size_t)(brow + 48) * K + q * 8);

    int cur = 0;
    for (int it = 0; it < nIters; it += 2) {
        // ---- first half: compute it (Bh in bhA*), prefetch it+1 ----
        __syncthreads();
        if (it + 1 < nIters) {
            char* base = smem + (cur ^ 1) * 16384;
            int ks2 = (it + 1) << 5;
#pragma unroll
            for (int j = 0; j < 2; ++j) {
                int wc  = wv * 2 + j;
                int row = wc * 16 + r0;
                size_t ga = (size_t)(m0 + row) * K + ks2 + kcs;
                size_t gb = (size_t)(n0 + row) * K + ks2 + kcs;
                int lofs = wc * 1024;
                __builtin_amdgcn_global_load_lds(
                    (const __attribute__((address_space(1))) void*)(A + ga),
                    (__attribute__((address_space(3))) void*)(base + lofs), 16, 0, 0);
                __builtin_amdgcn_global_load_lds(
                    (const __attribute__((address_space(1))) void*)(Bl + gb),
                    (__attribute__((address_space(3))) void*)(base + 8192 + lofs), 16, 0, 0);
            }
            bhB0 = *(const f16x8*)(Bh + (size_t)(brow)      * K + ks2 + q * 8);
            bhB1 = *(const f16x8*)(Bh + (size_t)(brow + 16) * K + ks2 + q * 8);
            bhB2 = *(const f16x8*)(Bh + (size_t)(brow + 32) * K + ks2 + q * 8);
            bhB3 = *(const f16x8*)(Bh + (size_t)(brow + 48) * K + ks2 + q * 8);
        }
        {
            _Float16* cA  = (_Float16*)(smem + cur * 16384);
            _Float16* cBl = (_Float16*)(smem + cur * 16384 + 8192);
            f16x8 ah[4];
#pragma unroll
            for (int mi = 0; mi < 4; ++mi)
                ah[mi] = *(const f16x8*)&cA[(wm * 64 + mi * 16 + fm) * 32 + qa * 8];
#pragma unroll
            for (int ni = 0; ni < 4; ++ni) {
                f16x8 bh = (ni == 0) ? bhA0 : (ni == 1) ? bhA1 : (ni == 2) ? bhA2 : bhA3;
                f16x8 bl = *(const f16x8*)&cBl[(wn * 64 + ni * 16 + fm) * 32 + qa * 8];
#pragma unroll
                for (int mi = 0; mi < 4; ++mi) {
                    acc[mi][ni] = __builtin_amdgcn_mfma_f32_16x16x32_f16(ah[mi], bh, acc[mi][ni], 0, 0, 0);
                    acc[mi][ni] = __builtin_amdgcn_mfma_f32_16x16x32_f16(ah[mi], bl, acc[mi][ni], 0, 0, 0);
                }
            }
            cur ^= 1;
        }
        if (it + 1 >= nIters) break;

        // ---- second half: compute it+1 (Bh in bhB*), prefetch it+2 ----
        __syncthreads();
        if (it + 2 < nIters) {
            char* base = smem + (cur ^ 1) * 16384;
            int ks2 = (it + 2) << 5;
#pragma unroll
            for (int j = 0; j < 2; ++j) {
                int wc  = wv * 2 + j;
                int row = wc * 16 + r0;
                size_t ga = (size_t)(m0 + row) * K + ks2 + kcs;
                size_t gb = (size_t)(n0 + row) * K + ks2 + kcs;
                int lofs = wc * 1024;
                __builtin_amdgcn_global_load_lds(
                    (const __attribute__((address_space(1))) void*)(A + ga),
                    (__attribute__((address_space(3))) void*)(base + lofs), 16, 0, 0);
                __builtin_amdgcn_global_load_lds(
                    (const __attribute__((address_space(1))) void*)(Bl + gb),
                    (__attribute__((address_space(3))) void*)(base + 8192 + lofs), 16, 0, 0);
            }
            bhA0 = *(const f16x8*)(Bh + (size_t)(brow)      * K + ks2 + q * 8);
            bhA1 = *(const f16x8*)(Bh + (size_t)(brow + 16) * K + ks2 + q * 8);
            bhA2 = *(const f16x8*)(Bh + (size_t)(brow + 32) * K + ks2 + q * 8);
            bhA3 = *(const f16x8*)(Bh + (size_t)(brow + 48) * K + ks2 + q * 8);
        }
        {
            _Float16* cA  = (_Float16*)(smem + cur * 16384);
            _Float16* cBl = (_Float16*)(smem + cur * 16384 + 8192);
            f16x8 ah[4];
#pragma unroll
            for (int mi = 0; mi < 4; ++mi)
                ah[mi] = *(const f16x8*)&cA[(wm * 64 + mi * 16 + fm) * 32 + qa * 8];
#pragma unroll
            for (int ni = 0; ni < 4; ++ni) {
                f16x8 bh = (ni == 0) ? bhB0 : (ni == 1) ? bhB1 : (ni == 2) ? bhB2 : bhB3;
                f16x8 bl = *(const f16x8*)&cBl[(wn * 64 + ni * 16 + fm) * 32 + qa * 8];
#pragma unroll
                for (int mi = 0; mi < 4; ++mi) {
                    acc[mi][ni] = __builtin_amdgcn_mfma_f32_16x16x32_f16(ah[mi], bh, acc[mi][ni], 0, 0, 0);
                    acc[mi][ni] = __builtin_amdgcn_mfma_f32_16x16x32_f16(ah[mi], bl, acc[mi][ni], 0, 0, 0);
                }
            }
            cur ^= 1;
        }
    }

    float bsv[4];
#pragma unroll
    for (int ni = 0; ni < 4; ++ni) {
        int col = n0 + wn * 64 + ni * 16 + fm;
        bsv[ni] = (col < Nh_) ? biasL[col] : biasR[col - Nh_];
    }

    _Float16* dstbase = (n0 < Nh_) ? P : Q;
    const int col0 = (n0 < Nh_) ? n0 : (n0 - Nh_);

#pragma unroll
    for (int c = 0; c < 2; ++c) {
        __syncthreads();
        if (wm == c) {
#pragma unroll
            for (int mi = 0; mi < 4; ++mi)
#pragma unroll
                for (int ni = 0; ni < 4; ++ni) {
                    int base = (mi * 16 + q * 4) * SCW + wn * 64 + ni * 16 + fm;
                    sC[base]           = acc[mi][ni].x + bsv[ni];
                    sC[base + SCW]     = acc[mi][ni].y + bsv[ni];
                    sC[base + 2 * SCW] = acc[mi][ni].z + bsv[ni];
                    sC[base + 3 * SCW] = acc[mi][ni].w + bsv[ni];
                }
        }
        __syncthreads();
#pragma unroll
        for (int j = 0; j < 8; ++j) {
            int flat = j * 256 + tid;
            int row  = flat >> 5;
            int col  = (flat & 31) * 4;
            f32x4 v = *(const f32x4*)(sC + row * SCW + col);
            f16x4 hv;
            hv.x = (_Float16)v.x; hv.y = (_Float16)v.y;
            hv.z = (_Float16)v.z; hv.w = (_Float16)v.w;
            *(f16x4*)(dstbase + (size_t)(m0 + c * 64 + row) * Nh_ + col0 + col) = hv;
        }
    }
}

// --------------------- fused edge kernels (1 wave/node) --------------------
// 4 heads x 128ch. P,Q fp16 stride 512. One wave per node; 128-thread blocks.
// Lean loop: SALU gather addressing, one-group-ahead src prefetch, DPP reduce.

// single-edge body (tail use); s is an SGPR-uniform node index.
__device__ __forceinline__ void edge4_one(
    int s, const _Float16* __restrict__ P, int c0,
    const f16x2* r2, const f16x2* t2, float& l_run, float* acc) {
    union { f16x8 v; f16x2 p[4]; } h;
    h.v = *(const f16x8*)(P + ((size_t)s << 9) + c0);
    float p = 0.f;
#pragma unroll
    for (int k = 0; k < 4; ++k)
        p = __builtin_amdgcn_fdot2(pk_leaky(h.p[k] + r2[k]), t2[k], p, false);
    p = dpp_sum16(p);
    float w = __expf(p);
    l_run += w;
#pragma unroll
    for (int j = 0; j < 8; ++j)
        acc[j] = fmaf((float)h.v[j], w, acc[j]);
}

__global__ __launch_bounds__(128) void gat_edge4_kernel(
    const _Float16* __restrict__ P, const _Float16* __restrict__ Q,
    const float* __restrict__ att, const float* __restrict__ bias,
    const int* __restrict__ rowstart, const int* __restrict__ srcs,
    _Float16* __restrict__ H, int N) {
    int wv = threadIdx.x >> 6;
    int lane = threadIdx.x & 63;
    int n = blockIdx.x * 2 + wv;
    if (n >= N) return;
    int c0 = lane * 8;

    f16x8 rv = *(const f16x8*)(Q + (size_t)n * 512 + c0);
    f16x2 r2[4], t2[4];
#pragma unroll
    for (int k = 0; k < 4; ++k) {
        r2[k].x = rv[2 * k]; r2[k].y = rv[2 * k + 1];
        t2[k].x = (_Float16)att[c0 + 2 * k];
        t2[k].y = (_Float16)att[c0 + 2 * k + 1];
    }

    float acc[8];
#pragma unroll
    for (int j = 0; j < 8; ++j) acc[j] = 0.f;
    float l_run = 0.f;

    int beg = __builtin_amdgcn_readfirstlane(rowstart[n]);
    int end = __builtin_amdgcn_readfirstlane(rowstart[n + 1]);

    int i = beg;
    int s0 = srcs[i], s1 = srcs[i + 1], s2 = srcs[i + 2], s3 = srcs[i + 3];

    for (; i + 3 < end; ) {
        int f0 = srcs[i + 4], f1 = srcs[i + 5], f2 = srcs[i + 6], f3 = srcs[i + 7];
        int u0 = __builtin_amdgcn_readfirstlane(s0);
        int u1 = __builtin_amdgcn_readfirstlane(s1);
        int u2 = __builtin_amdgcn_readfirstlane(s2);
        int u3 = __builtin_amdgcn_readfirstlane(s3);
        union { f16x8 v; f16x2 p[4]; } h0, h1, h2, h3;
        h0.v = *(const f16x8*)(P + ((size_t)u0 << 9) + c0);
        h1.v = *(const f16x8*)(P + ((size_t)u1 << 9) + c0);
        h2.v = *(const f16x8*)(P + ((size_t)u2 << 9) + c0);
        h3.v = *(const f16x8*)(P + ((size_t)u3 << 9) + c0);
        float p0 = 0.f, p1 = 0.f, p2 = 0.f, p3 = 0.f;
#pragma unroll
        for (int k = 0; k < 4; ++k) {
            p0 = __builtin_amdgcn_fdot2(pk_leaky(h0.p[k] + r2[k]), t2[k], p0, false);
            p1 = __builtin_amdgcn_fdot2(pk_leaky(h1.p[k] + r2[k]), t2[k], p1, false);
            p2 = __builtin_amdgcn_fdot2(pk_leaky(h2.p[k] + r2[k]), t2[k], p2, false);
            p3 = __builtin_amdgcn_fdot2(pk_leaky(h3.p[k] + r2[k]), t2[k], p3, false);
        }
        p0 = dpp_sum16(p0);
        p1 = dpp_sum16(p1);
        p2 = dpp_sum16(p2);
        p3 = dpp_sum16(p3);
        float w0 = __expf(p0);
        float w1 = __expf(p1);
        float w2 = __expf(p2);
        float w3 = __expf(p3);
        l_run += (w0 + w1) + (w2 + w3);
#pragma unroll
        for (int j = 0; j < 8; ++j) {
            float a = fmaf((float)h0.v[j], w0, acc[j]);
            a = fmaf((float)h1.v[j], w1, a);
            a = fmaf((float)h2.v[j], w2, a);
            acc[j] = fmaf((float)h3.v[j], w3, a);
        }
        i += 4; s0 = f0; s1 = f1; s2 = f2; s3 = f3;
    }
    int rem = end - i;   // 0..3
    if (rem > 0) edge4_one(__builtin_amdgcn_readfirstlane(s0), P, c0, r2, t2, l_run, acc);
    if (rem > 1) edge4_one(__builtin_amdgcn_readfirstlane(s1), P, c0, r2, t2, l_run, acc);
    if (rem > 2) edge4_one(__builtin_amdgcn_readfirstlane(s2), P, c0, r2, t2, l_run, acc);

    float inv = 1.f / l_run;
    f16x8 oh;
#pragma unroll
    for (int j = 0; j < 8; ++j)
        oh[j] = (_Float16)elu1(acc[j] * inv + bias[c0 + j]);
    *(f16x8*)(H + (size_t)n * 512 + c0) = oh;
}

// 1 head x 128ch (layer 3). P,Q fp16 stride 128. One wave per node; 128-thr
// blocks. Quarter-wave per edge; DPP width-16 reduce; plain loop.
__global__ __launch_bounds__(128) void gat_edge1_kernel(
    const _Float16* __restrict__ P, const _Float16* __restrict__ Q,
    const float* __restrict__ att, const float* __restrict__ bias,
    const int* __restrict__ rowstart, const int* __restrict__ srcs,
    float* __restrict__ out, int N) {
    int wv = threadIdx.x >> 6;
    int lane = threadIdx.x & 63;
    int n = blockIdx.x * 2 + wv;
    if (n >= N) return;
    int qd = lane >> 4;          // quarter 0..3 (edge slot)
    int lq = lane & 15;
    int c0 = lq * 8;             // 8 channels per lane, 16 lanes = 128 ch

    f16x8 rv = *(const f16x8*)(Q + (size_t)n * 128 + c0);
    f16x2 r2[4], t2[4];
#pragma unroll
    for (int k = 0; k < 4; ++k) {
        r2[k].x = rv[2 * k]; r2[k].y = rv[2 * k + 1];
        t2[k].x = (_Float16)att[c0 + 2 * k];
        t2[k].y = (_Float16)att[c0 + 2 * k + 1];
    }

    float acc[8];
#pragma unroll
    for (int j = 0; j < 8; ++j) acc[j] = 0.f;
    float l_run = 0.f;

    int beg = __builtin_amdgcn_readfirstlane(rowstart[n]);
    int end = __builtin_amdgcn_readfirstlane(rowstart[n + 1]);
    for (int e = beg + qd; e < end; e += 4) {
        int s = srcs[e];
        union { f16x8 v; f16x2 p[4]; } hv;
        hv.v = *(const f16x8*)(P + ((size_t)s << 7) + c0);
        float p = 0.f;
#pragma unroll
        for (int k = 0; k < 4; ++k)
            p = __builtin_amdgcn_fdot2(pk_leaky(hv.p[k] + r2[k]), t2[k], p, false);
        p = dpp_sum16(p);
        float w = __expf(p);
        l_run += w;
#pragma unroll
        for (int j = 0; j < 8; ++j)
            acc[j] = fmaf((float)hv.v[j], w, acc[j]);
    }
    // cross-quarter reduction (quarters processed disjoint edge subsets)
    l_run += __shfl_xor(l_run, 16, 64);
    l_run += __shfl_xor(l_run, 32, 64);
#pragma unroll
    for (int j = 0; j < 8; ++j) {
        acc[j] += __shfl_xor(acc[j], 16, 64);
        acc[j] += __shfl_xor(acc[j], 32, 64);
    }
    float inv = 1.f / l_run;
    int cw = c0 + qd * 2;
    float2 w2;
    w2.x = elu1(acc[qd * 2]     * inv + bias[cw]);
    w2.y = elu1(acc[qd * 2 + 1] * inv + bias[cw + 1]);
    *(float2*)(out + (size_t)n * 128 + cw) = w2;
}

// -------------------- fused pool (segmented) + MLP -------------------------
__global__ __launch_bounds__(256) void poolmlp_kernel(
    const float* __restrict__ h3, const int* __restrict__ gstart,
    const float* __restrict__ W1, const float* __restrict__ b1,
    const float* __restrict__ W2, const float* __restrict__ b2,
    float* __restrict__ out) {
    __shared__ float red[256];
    __shared__ float pr[128];
    __shared__ float2 mred[128];
    int g = blockIdx.x;
    int t = threadIdx.x;
    int c = t & 127;
    int h = t >> 7;    // 0/1
    int gs = gstart[g], ge = gstart[g + 1];
    float s = 0.f;
    for (int n = gs + h; n < ge; n += 2) s += h3[(size_t)n * 128 + c];
    red[t] = s;
    __syncthreads();
    if (h == 0) {
        float tot = red[c] + red[c + 128];
        float cntf = fmaxf((float)(ge - gs), 1.f);
        pr[c] = tot / cntf;
    }
    __syncthreads();
    if (t < 128) {
        float hh = b1[t];
#pragma unroll 4
        for (int k = 0; k < 128; ++k) hh = fmaf(pr[k], W1[k * 128 + t], hh);
        hh = fmaxf(hh, 0.0f);
        mred[t] = make_float2(hh * W2[t * 2], hh * W2[t * 2 + 1]);
    }
    __syncthreads();
    for (int ss = 64; ss > 0; ss >>= 1) {
        if (t < ss) {
            mred[t].x += mred[t + ss].x;
            mred[t].y += mred[t + ss].y;
        }
        __syncthreads();
    }
    if (t == 0) {
        out[g * 2]     = mred[0].x + b2[0];
        out[g * 2 + 1] = mred[0].y + b2[1];
    }
}

// ------------------------------ launch -------------------------------------
extern "C" void kernel_launch(void* const* d_in, const int* in_sizes, int n_in,
                              void* d_out, int out_size, void* d_ws, size_t ws_size,
                              hipStream_t stream) {
    const float* x     = (const float*)d_in[0];
    const int*   esrc  = (const int*)d_in[1];
    const int*   edst  = (const int*)d_in[2];
    const int*   batch = (const int*)d_in[3];
    const float* Wl1   = (const float*)d_in[4];
    const float* Wr1   = (const float*)d_in[5];
    const float* bl1   = (const float*)d_in[6];
    const float* br1   = (const float*)d_in[7];
    const float* att1  = (const float*)d_in[8];
    const float* bias1 = (const float*)d_in[9];
    const float* Wl2   = (const float*)d_in[10];
    const float* Wr2   = (const float*)d_in[11];
    const float* bl2   = (const float*)d_in[12];
    const float* br2   = (const float*)d_in[13];
    const float* att2  = (const float*)d_in[14];
    const float* bias2 = (const float*)d_in[15];
    const float* Wl3   = (const float*)d_in[16];
    const float* Wr3   = (const float*)d_in[17];
    const float* bl3   = (const float*)d_in[18];
    const float* br3   = (const float*)d_in[19];
    const float* att3  = (const float*)d_in[20];
    const float* bias3 = (const float*)d_in[21];
    const float* Wm1   = (const float*)d_in[22];
    const float* bm1   = (const float*)d_in[23];
    const float* Wm2   = (const float*)d_in[24];
    const float* bm2   = (const float*)d_in[25];

    int N  = in_sizes[0] / 128;        // 20000
    int E  = in_sizes[1];              // 320000
    int ET = E + N;
    int B  = out_size / 2;             // 64 graphs
    const int Mp = 160 * 128;          // 20480 rows (8-tile-aligned for swizzle)
    int nch = (N + 255) / 256;         // scan chunks

    // --- workspace carve-up ---
    char* ws = (char*)d_ws;
    size_t off = 0;
    auto alloc = [&](size_t bytes) -> void* {
        void* p = ws + off;
        off += (bytes + 255) & ~(size_t)255;
        return p;
    };
    _Float16* P    = (_Float16*)alloc((size_t)Mp * 512 * 2);  // xl gather table
    _Float16* Q    = (_Float16*)alloc((size_t)Mp * 512 * 2);  // xr (fp16)
    _Float16* A1   = (_Float16*)alloc((size_t)Mp * 128 * 2);  // fp16(x)
    _Float16* Hb   = (_Float16*)alloc((size_t)Mp * 512 * 2);  // edge out / next A
    _Float16* Wth1 = (_Float16*)alloc((size_t)1024 * 128 * 2);
    _Float16* Wtl1 = (_Float16*)alloc((size_t)1024 * 128 * 2);
    _Float16* Wth2 = (_Float16*)alloc((size_t)1024 * 512 * 2);
    _Float16* Wtl2 = (_Float16*)alloc((size_t)1024 * 512 * 2);
    _Float16* Wth3 = (_Float16*)alloc((size_t)256 * 512 * 2);
    _Float16* Wtl3 = (_Float16*)alloc((size_t)256 * 512 * 2);
    float*    R3   = (float*)alloc((size_t)Mp * 128 * 4);     // layer-3 edge out
    int*    cnt      = (int*)alloc((size_t)N * 4);
    int*    psum     = (int*)alloc((size_t)(nch + 1) * 4);
    int*    rowstart = (int*)alloc((size_t)(N + 1) * 4);
    int*    cursor   = (int*)alloc((size_t)N * 4);
    int*    csr_src  = (int*)alloc((size_t)ET * 4 + 64);      // +pad for prefetch over-read
    int*    gstart   = (int*)alloc((size_t)(B + 1) * 4);
    (void)ws_size;

    // --- zero cnt (memset, no launch) ---
    hipMemsetAsync(cnt, 0, (size_t)N * 4, stream);

    // --- fused prep (convWT x3, convA, boundary, degree count) ---
    int cblocks = (ET + 255) / 256;
    prep_kernel<<<3407 + cblocks, 256, 0, stream>>>(
        Wl1, Wr1, Wth1, Wtl1, Wl2, Wr2, Wth2, Wtl2, Wl3, Wr3, Wth3, Wtl3,
        x, A1, N * 128, Mp * 128, batch, gstart, N, B, edst, cnt, E);

    // --- CSR build (3-phase scan) + scatter ---
    scan1_kernel<<<nch, 256, 0, stream>>>(cnt, psum, N);
    scan2_kernel<<<1, 128, 0, stream>>>(psum, nch);
    scan3_kernel<<<nch, 256, 0, stream>>>(cnt, psum, rowstart, cursor, N);
    scatter_kernel<<<cblocks, 256, 0, stream>>>(esrc, edst, cursor, csr_src, E, N);

    int eblocks = (N + 1) / 2;

    // --- layer 1: fused N=1024 GEMM -> P | Q (fp16) ---
    gemm_f16_kernel<<<160 * 8, 256, 0, stream>>>(A1, Wth1, Wtl1, bl1, br1, 512, P, Q, 128, 8);
    gat_edge4_kernel<<<eblocks, 128, 0, stream>>>(P, Q, att1, bias1, rowstart, csr_src, Hb, N);

    // --- layer 2 ---
    gemm_f16_kernel<<<160 * 8, 256, 0, stream>>>(Hb, Wth2, Wtl2, bl2, br2, 512, P, Q, 512, 8);
    gat_edge4_kernel<<<eblocks, 128, 0, stream>>>(P, Q, att2, bias2, rowstart, csr_src, Hb, N);

    // --- layer 3 (1 head): fused N=256 GEMM -> P | Q (fp16), ld=128 ---
    gemm_f16_kernel<<<160 * 2, 256, 0, stream>>>(Hb, Wth3, Wtl3, bl3, br3, 128, P, Q, 512, 2);
    gat_edge1_kernel<<<eblocks, 128, 0, stream>>>(P, Q, att3, bias3, rowstart, csr_src, R3, N);

    // --- fused pool + MLP ---
    poolmlp_kernel<<<B, 256, 0, stream>>>(R3, gstart, Wm1, bm1, Wm2, bm2, (float*)d_out);
}

// Round 13
// 393.959 us; speedup vs baseline: 1.1715x; 1.1715x over previous
//
#include <hip/hip_runtime.h>
#include <math.h>

// ---------------------------------------------------------------------------
// GATv2 x3 + global_mean_pool + MLP, MI355X (gfx950).
// R31: revert R30's register-Bh pipeline (VGPR 80->152, occupancy 10%,
// gemm 52->90us). GEMM restored to the R27/R29 measured optimum: A/Bh/Bl all
// staged via global_load_lds, 48KB LDS double-buffer, XOR swizzle
// (0 bank conflicts, 826 TF = 91% of this structure's ceiling). The
// {LDS, VGPR, prefetch-distance} triangle has been rebalanced 3 ways
// (R28/R30 vs R29); R29's point wins every time — treated as final.
// Board: edge4 at random-gather delivery floor (~51us, 6.8TB/s effective);
// launch gaps ~0.5us; CSR/prep/pool fused. Config = session optimum.
// ---------------------------------------------------------------------------

typedef __attribute__((ext_vector_type(4))) float f32x4;
typedef __attribute__((ext_vector_type(8))) _Float16 f16x8;
typedef __attribute__((ext_vector_type(4))) _Float16 f16x4;
typedef __attribute__((ext_vector_type(2))) _Float16 f16x2;

__device__ __forceinline__ float elu1(float x) {
    return (x > 0.f) ? x : (__expf(x) - 1.f);
}
// packed leaky: max(s, 0.2*s) elementwise (valid for slope<1)
__device__ __forceinline__ f16x2 pk_leaky(f16x2 s) {
    const f16x2 slope = {(_Float16)0.2f, (_Float16)0.2f};
    return __builtin_elementwise_max(s, s * slope);
}

// 16-lane row sum via DPP mov (compiler-managed hazards).
__device__ __forceinline__ float dpp_sum16(float v) {
    int t;
    t = __builtin_amdgcn_mov_dpp(__float_as_int(v), 0xB1, 0xF, 0xF, true);
    v += __int_as_float(t);
    t = __builtin_amdgcn_mov_dpp(__float_as_int(v), 0x4E, 0xF, 0xF, true);
    v += __int_as_float(t);
    t = __builtin_amdgcn_mov_dpp(__float_as_int(v), 0x141, 0xF, 0xF, true);
    v += __int_as_float(t);
    t = __builtin_amdgcn_mov_dpp(__float_as_int(v), 0x140, 0xF, 0xF, true);
    v += __int_as_float(t);
    return v;
}

// ------------------------------ CSR build ---------------------------------
// 3-phase scan. S1: chunk sums (256 elems/chunk).
__global__ __launch_bounds__(256) void scan1_kernel(const int* __restrict__ cnt,
                                                    int* __restrict__ psum, int N) {
    __shared__ int red[256];
    int idx = blockIdx.x * 256 + threadIdx.x;
    red[threadIdx.x] = (idx < N) ? cnt[idx] : 0;
    __syncthreads();
    for (int s = 128; s > 0; s >>= 1) {
        if (threadIdx.x < s) red[threadIdx.x] += red[threadIdx.x + s];
        __syncthreads();
    }
    if (threadIdx.x == 0) psum[blockIdx.x] = red[0];
}
// S2: exclusive scan of nch partials — 128-wide Hillis-Steele (nch <= 128).
__global__ __launch_bounds__(128) void scan2_kernel(int* __restrict__ psum, int nch) {
    __shared__ int buf[128];
    int t = threadIdx.x;
    int v = (t < nch) ? psum[t] : 0;
    buf[t] = v;
    __syncthreads();
    for (int off = 1; off < 128; off <<= 1) {
        int x = (t >= off) ? buf[t - off] : 0;
        __syncthreads();
        buf[t] += x;
        __syncthreads();
    }
    if (t < nch) psum[t] = buf[t] - v;   // exclusive
}
// S3: per-chunk inclusive scan (coalesced) + chunk offset -> rowstart/cursor.
__global__ __launch_bounds__(256) void scan3_kernel(const int* __restrict__ cnt,
                                                    const int* __restrict__ psum,
                                                    int* __restrict__ rowstart,
                                                    int* __restrict__ cursor, int N) {
    __shared__ int buf[256];
    int idx = blockIdx.x * 256 + threadIdx.x;
    int v = (idx < N) ? cnt[idx] : 0;
    buf[threadIdx.x] = v;
    __syncthreads();
    for (int off = 1; off < 256; off <<= 1) {
        int t = (threadIdx.x >= off) ? buf[threadIdx.x - off] : 0;
        __syncthreads();
        buf[threadIdx.x] += t;
        __syncthreads();
    }
    int excl = buf[threadIdx.x] - v + psum[blockIdx.x];
    if (idx < N) {
        rowstart[idx] = excl;
        cursor[idx]   = excl;
        if (idx == N - 1) rowstart[N] = excl + v;
    }
}

__global__ void scatter_kernel(const int* __restrict__ src, const int* __restrict__ dst,
                               int* __restrict__ cursor, int* __restrict__ csr_src,
                               int E, int N) {
    int e = blockIdx.x * 256 + threadIdx.x;
    if (e < E + N) {
        int d, s;
        if (e < E) { d = dst[e]; s = src[e]; }
        else       { d = e - E; s = e - E; }
        int pos = atomicAdd(&cursor[d], 1);
        csr_src[pos] = s;
    }
}

// ------- fused prep: convWT x3 + convA + boundary + degree count -----------
// All roles are mutually independent; dispatched by blockIdx.x range.
__device__ __forceinline__ void convWT_body(
    const float* __restrict__ Wl, const float* __restrict__ Wr,
    _Float16* __restrict__ Bth, _Float16* __restrict__ Btl,
    int K, int Nh, int bx, int by, int t) {
    __shared__ float tile[32][33];
    int kb = bx * 32;
    int nb = by * 32;
    int tx = t & 31;
    int ty = t >> 5;     // 0..7
#pragma unroll
    for (int j = 0; j < 4; ++j) {
        int kk = kb + ty + j * 8;
        int nn = nb + tx;
        float v = (nn < Nh) ? Wl[(size_t)kk * Nh + nn]
                            : Wr[(size_t)kk * Nh + (nn - Nh)];
        tile[ty + j * 8][tx] = v;
    }
    __syncthreads();
#pragma unroll
    for (int j = 0; j < 4; ++j) {
        int nn = nb + ty + j * 8;
        int kk = kb + tx;
        float v = tile[tx][ty + j * 8];
        _Float16 h = (_Float16)v;
        Bth[(size_t)nn * K + kk] = h;
        Btl[(size_t)nn * K + kk] = (_Float16)(v - (float)h);
    }
}

__global__ __launch_bounds__(256) void prep_kernel(
    const float* __restrict__ Wl1, const float* __restrict__ Wr1,
    _Float16* __restrict__ Wth1, _Float16* __restrict__ Wtl1,
    const float* __restrict__ Wl2, const float* __restrict__ Wr2,
    _Float16* __restrict__ Wth2, _Float16* __restrict__ Wtl2,
    const float* __restrict__ Wl3, const float* __restrict__ Wr3,
    _Float16* __restrict__ Wth3, _Float16* __restrict__ Wtl3,
    const float* __restrict__ X, _Float16* __restrict__ A,
    int n_valid, int n_total,
    const int* __restrict__ batch, int* __restrict__ gstart, int N, int B,
    const int* __restrict__ edst, int* __restrict__ cnt, int E) {
    int b = blockIdx.x;
    int t = threadIdx.x;
    if (b < 128) {                       // convWT1: K=128, Nh=512
        convWT_body(Wl1, Wr1, Wth1, Wtl1, 128, 512, b & 3, b >> 2, t);
    } else if (b < 640) {                // convWT2: K=512, Nh=512
        int l = b - 128;
        convWT_body(Wl2, Wr2, Wth2, Wtl2, 512, 512, l & 15, l >> 4, t);
    } else if (b < 768) {                // convWT3: K=512, Nh=128
        int l = b - 640;
        convWT_body(Wl3, Wr3, Wth3, Wtl3, 512, 128, l & 15, l >> 4, t);
    } else if (b < 3328) {               // convA: fp32 -> fp16, 4 elems/thread
        int i = ((b - 768) * 256 + t) * 4;
        if (i < n_total) {
            float4 v = (i < n_valid) ? *(const float4*)(X + i)
                                     : make_float4(0.f, 0.f, 0.f, 0.f);
            f16x4 h;
            h.x = (_Float16)v.x; h.y = (_Float16)v.y;
            h.z = (_Float16)v.z; h.w = (_Float16)v.w;
            *(f16x4*)(A + i) = h;
        }
    } else if (b < 3407) {               // boundary: gstart from sorted batch
        int n = (b - 3328) * 256 + t;
        if (n > N) return;
        int cur  = (n < N) ? batch[n] : B;
        int prev = (n == 0) ? -1 : batch[n - 1];
        for (int g = prev + 1; g <= cur; ++g) gstart[g] = n;
    } else {                             // count: degree histogram (+selfloop)
        int e = (b - 3407) * 256 + t;
        if (e < E + N) {
            int d = (e < E) ? edst[e] : (e - E);
            atomicAdd(&cnt[d], 1);
        }
    }
}

// --------------------------- f16 2-product MFMA GEMM -----------------------
// Logical C[Mp x 2Nh] = A x B + bias; left half -> P, right half -> Q (both
// fp16). DMA double-buffer. LDS tiles XOR-swizzled: position (row, slot)
// holds data slot^((row>>1)&3); staging pre-permutes the per-lane global
// k-offset (same 64B line), reads XOR q. Conflict-free ds_read_b128.
#define SCW 132   // epilogue LDS row stride (f32)
__global__ __launch_bounds__(256, 1) void gemm_f16_kernel(
    const _Float16* __restrict__ A,
    const _Float16* __restrict__ Bh, const _Float16* __restrict__ Bl,
    const float* __restrict__ biasL, const float* __restrict__ biasR, int Nh_,
    _Float16* __restrict__ P, _Float16* __restrict__ Q, int K, int NT) {
    __shared__ __align__(16) char smem[49152];
    float* sC = (float*)(smem);   // epilogue reuse (64*SCW*4 = 33.8KB)

    const int tid  = threadIdx.x;
    const int lane = tid & 63;
    const int wv   = tid >> 6;
    const int wm   = wv & 1;
    const int wn   = wv >> 1;
    const int fm   = lane & 15;
    const int q    = lane >> 4;
    const int qa   = q ^ ((fm >> 1) & 3);   // swizzled read slot

    const int bi = blockIdx.x;
    const int kx = bi & 7;
    const int tt = bi >> 3;
    const int m0 = ((tt / NT) * 8 + kx) * 128;
    const int n0 = (tt % NT) * 128;

    const int r0  = lane >> 2;
    // swizzled per-lane source k-offset: slot_src = (lane&3) ^ ((lane>>3)&3)
    const int kcs = (((lane & 3) ^ ((lane >> 3) & 3)) << 3);

    f32x4 acc[4][4];
#pragma unroll
    for (int i = 0; i < 4; ++i)
#pragma unroll
        for (int j = 0; j < 4; ++j) {
            acc[i][j].x = 0.f; acc[i][j].y = 0.f;
            acc[i][j].z = 0.f; acc[i][j].w = 0.f;
        }

    const int nIters = K >> 5;
    int cur = 0;
    {
        char* base = smem;
#pragma unroll
        for (int j = 0; j < 2; ++j) {
            int wc  = wv * 2 + j;
            int row = wc * 16 + r0;
            size_t ga = (size_t)(m0 + row) * K + kcs;
            size_t gb = (size_t)(n0 + row) * K + kcs;
            int lofs = wc * 1024;
            __builtin_amdgcn_global_load_lds(
                (const __attribute__((address_space(1))) void*)(A + ga),
                (__attribute__((address_space(3))) void*)(base + lofs), 16, 0, 0);
            __builtin_amdgcn_global_load_lds(
                (const __attribute__((address_space(1))) void*)(Bh + gb),
                (__attribute__((address_space(3))) void*)(base + 8192 + lofs), 16, 0, 0);
            __builtin_amdgcn_global_load_lds(
                (const __attribute__((address_space(1))) void*)(Bl + gb),
                (__attribute__((address_space(3))) void*)(base + 16384 + lofs), 16, 0, 0);
        }
    }
    for (int it = 0; it < nIters; ++it) {
        __syncthreads();
        if (it + 1 < nIters) {
            char* base = smem + (cur ^ 1) * 24576;
            int ks = (it + 1) << 5;
#pragma unroll
            for (int j = 0; j < 2; ++j) {
                int wc  = wv * 2 + j;
                int row = wc * 16 + r0;
                size_t ga = (size_t)(m0 + row) * K + ks + kcs;
                size_t gb = (size_t)(n0 + row) * K + ks + kcs;
                int lofs = wc * 1024;
                __builtin_amdgcn_global_load_lds(
                    (const __attribute__((address_space(1))) void*)(A + ga),
                    (__attribute__((address_space(3))) void*)(base + lofs), 16, 0, 0);
                __builtin_amdgcn_global_load_lds(
                    (const __attribute__((address_space(1))) void*)(Bh + gb),
                    (__attribute__((address_space(3))) void*)(base + 8192 + lofs), 16, 0, 0);
                __builtin_amdgcn_global_load_lds(
                    (const __attribute__((address_space(1))) void*)(Bl + gb),
                    (__attribute__((address_space(3))) void*)(base + 16384 + lofs), 16, 0, 0);
            }
        }

        _Float16* cA  = (_Float16*)(smem + cur * 24576);
        _Float16* cBh = (_Float16*)(smem + cur * 24576 + 8192);
        _Float16* cBl = (_Float16*)(smem + cur * 24576 + 16384);
        f16x8 ah[4];
#pragma unroll
        for (int mi = 0; mi < 4; ++mi)
            ah[mi] = *(const f16x8*)&cA[(wm * 64 + mi * 16 + fm) * 32 + qa * 8];
#pragma unroll
        for (int ni = 0; ni < 4; ++ni) {
            int r = (wn * 64 + ni * 16 + fm) * 32 + qa * 8;
            f16x8 bh = *(const f16x8*)&cBh[r];
            f16x8 bl = *(const f16x8*)&cBl[r];
#pragma unroll
            for (int mi = 0; mi < 4; ++mi) {
                acc[mi][ni] = __builtin_amdgcn_mfma_f32_16x16x32_f16(ah[mi], bh, acc[mi][ni], 0, 0, 0);
                acc[mi][ni] = __builtin_amdgcn_mfma_f32_16x16x32_f16(ah[mi], bl, acc[mi][ni], 0, 0, 0);
            }
        }
        cur ^= 1;
    }

    float bsv[4];
#pragma unroll
    for (int ni = 0; ni < 4; ++ni) {
        int col = n0 + wn * 64 + ni * 16 + fm;
        bsv[ni] = (col < Nh_) ? biasL[col] : biasR[col - Nh_];
    }

    _Float16* dstbase = (n0 < Nh_) ? P : Q;
    const int col0 = (n0 < Nh_) ? n0 : (n0 - Nh_);

#pragma unroll
    for (int c = 0; c < 2; ++c) {
        __syncthreads();
        if (wm == c) {
#pragma unroll
            for (int mi = 0; mi < 4; ++mi)
#pragma unroll
                for (int ni = 0; ni < 4; ++ni) {
                    int base = (mi * 16 + q * 4) * SCW + wn * 64 + ni * 16 + fm;
                    sC[base]           = acc[mi][ni].x + bsv[ni];
                    sC[base + SCW]     = acc[mi][ni].y + bsv[ni];
                    sC[base + 2 * SCW] = acc[mi][ni].z + bsv[ni];
                    sC[base + 3 * SCW] = acc[mi][ni].w + bsv[ni];
                }
        }
        __syncthreads();
#pragma unroll
        for (int j = 0; j < 8; ++j) {
            int flat = j * 256 + tid;
            int row  = flat >> 5;
            int col  = (flat & 31) * 4;
            f32x4 v = *(const f32x4*)(sC + row * SCW + col);
            f16x4 hv;
            hv.x = (_Float16)v.x; hv.y = (_Float16)v.y;
            hv.z = (_Float16)v.z; hv.w = (_Float16)v.w;
            *(f16x4*)(dstbase + (size_t)(m0 + c * 64 + row) * Nh_ + col0 + col) = hv;
        }
    }
}

// --------------------- fused edge kernels (1 wave/node) --------------------
// 4 heads x 128ch. P,Q fp16 stride 512. One wave per node; 128-thread blocks.
// Lean loop: SALU gather addressing, one-group-ahead src prefetch, DPP reduce.

// single-edge body (tail use); s is an SGPR-uniform node index.
__device__ __forceinline__ void edge4_one(
    int s, const _Float16* __restrict__ P, int c0,
    const f16x2* r2, const f16x2* t2, float& l_run, float* acc) {
    union { f16x8 v; f16x2 p[4]; } h;
    h.v = *(const f16x8*)(P + ((size_t)s << 9) + c0);
    float p = 0.f;
#pragma unroll
    for (int k = 0; k < 4; ++k)
        p = __builtin_amdgcn_fdot2(pk_leaky(h.p[k] + r2[k]), t2[k], p, false);
    p = dpp_sum16(p);
    float w = __expf(p);
    l_run += w;
#pragma unroll
    for (int j = 0; j < 8; ++j)
        acc[j] = fmaf((float)h.v[j], w, acc[j]);
}

__global__ __launch_bounds__(128) void gat_edge4_kernel(
    const _Float16* __restrict__ P, const _Float16* __restrict__ Q,
    const float* __restrict__ att, const float* __restrict__ bias,
    const int* __restrict__ rowstart, const int* __restrict__ srcs,
    _Float16* __restrict__ H, int N) {
    int wv = threadIdx.x >> 6;
    int lane = threadIdx.x & 63;
    int n = blockIdx.x * 2 + wv;
    if (n >= N) return;
    int c0 = lane * 8;

    f16x8 rv = *(const f16x8*)(Q + (size_t)n * 512 + c0);
    f16x2 r2[4], t2[4];
#pragma unroll
    for (int k = 0; k < 4; ++k) {
        r2[k].x = rv[2 * k]; r2[k].y = rv[2 * k + 1];
        t2[k].x = (_Float16)att[c0 + 2 * k];
        t2[k].y = (_Float16)att[c0 + 2 * k + 1];
    }

    float acc[8];
#pragma unroll
    for (int j = 0; j < 8; ++j) acc[j] = 0.f;
    float l_run = 0.f;

    int beg = __builtin_amdgcn_readfirstlane(rowstart[n]);
    int end = __builtin_amdgcn_readfirstlane(rowstart[n + 1]);

    int i = beg;
    int s0 = srcs[i], s1 = srcs[i + 1], s2 = srcs[i + 2], s3 = srcs[i + 3];

    for (; i + 3 < end; ) {
        int f0 = srcs[i + 4], f1 = srcs[i + 5], f2 = srcs[i + 6], f3 = srcs[i + 7];
        int u0 = __builtin_amdgcn_readfirstlane(s0);
        int u1 = __builtin_amdgcn_readfirstlane(s1);
        int u2 = __builtin_amdgcn_readfirstlane(s2);
        int u3 = __builtin_amdgcn_readfirstlane(s3);
        union { f16x8 v; f16x2 p[4]; } h0, h1, h2, h3;
        h0.v = *(const f16x8*)(P + ((size_t)u0 << 9) + c0);
        h1.v = *(const f16x8*)(P + ((size_t)u1 << 9) + c0);
        h2.v = *(const f16x8*)(P + ((size_t)u2 << 9) + c0);
        h3.v = *(const f16x8*)(P + ((size_t)u3 << 9) + c0);
        float p0 = 0.f, p1 = 0.f, p2 = 0.f, p3 = 0.f;
#pragma unroll
        for (int k = 0; k < 4; ++k) {
            p0 = __builtin_amdgcn_fdot2(pk_leaky(h0.p[k] + r2[k]), t2[k], p0, false);
            p1 = __builtin_amdgcn_fdot2(pk_leaky(h1.p[k] + r2[k]), t2[k], p1, false);
            p2 = __builtin_amdgcn_fdot2(pk_leaky(h2.p[k] + r2[k]), t2[k], p2, false);
            p3 = __builtin_amdgcn_fdot2(pk_leaky(h3.p[k] + r2[k]), t2[k], p3, false);
        }
        p0 = dpp_sum16(p0);
        p1 = dpp_sum16(p1);
        p2 = dpp_sum16(p2);
        p3 = dpp_sum16(p3);
        float w0 = __expf(p0);
        float w1 = __expf(p1);
        float w2 = __expf(p2);
        float w3 = __expf(p3);
        l_run += (w0 + w1) + (w2 + w3);
#pragma unroll
        for (int j = 0; j < 8; ++j) {
            float a = fmaf((float)h0.v[j], w0, acc[j]);
            a = fmaf((float)h1.v[j], w1, a);
            a = fmaf((float)h2.v[j], w2, a);
            acc[j] = fmaf((float)h3.v[j], w3, a);
        }
        i += 4; s0 = f0; s1 = f1; s2 = f2; s3 = f3;
    }
    int rem = end - i;   // 0..3
    if (rem > 0) edge4_one(__builtin_amdgcn_readfirstlane(s0), P, c0, r2, t2, l_run, acc);
    if (rem > 1) edge4_one(__builtin_amdgcn_readfirstlane(s1), P, c0, r2, t2, l_run, acc);
    if (rem > 2) edge4_one(__builtin_amdgcn_readfirstlane(s2), P, c0, r2, t2, l_run, acc);

    float inv = 1.f / l_run;
    f16x8 oh;
#pragma unroll
    for (int j = 0; j < 8; ++j)
        oh[j] = (_Float16)elu1(acc[j] * inv + bias[c0 + j]);
    *(f16x8*)(H + (size_t)n * 512 + c0) = oh;
}

// 1 head x 128ch (layer 3). P,Q fp16 stride 128. One wave per node; 128-thr
// blocks. Quarter-wave per edge; DPP width-16 reduce; plain loop.
__global__ __launch_bounds__(128) void gat_edge1_kernel(
    const _Float16* __restrict__ P, const _Float16* __restrict__ Q,
    const float* __restrict__ att, const float* __restrict__ bias,
    const int* __restrict__ rowstart, const int* __restrict__ srcs,
    float* __restrict__ out, int N) {
    int wv = threadIdx.x >> 6;
    int lane = threadIdx.x & 63;
    int n = blockIdx.x * 2 + wv;
    if (n >= N) return;
    int qd = lane >> 4;          // quarter 0..3 (edge slot)
    int lq = lane & 15;
    int c0 = lq * 8;             // 8 channels per lane, 16 lanes = 128 ch

    f16x8 rv = *(const f16x8*)(Q + (size_t)n * 128 + c0);
    f16x2 r2[4], t2[4];
#pragma unroll
    for (int k = 0; k < 4; ++k) {
        r2[k].x = rv[2 * k]; r2[k].y = rv[2 * k + 1];
        t2[k].x = (_Float16)att[c0 + 2 * k];
        t2[k].y = (_Float16)att[c0 + 2 * k + 1];
    }

    float acc[8];
#pragma unroll
    for (int j = 0; j < 8; ++j) acc[j] = 0.f;
    float l_run = 0.f;

    int beg = __builtin_amdgcn_readfirstlane(rowstart[n]);
    int end = __builtin_amdgcn_readfirstlane(rowstart[n + 1]);
    for (int e = beg + qd; e < end; e += 4) {
        int s = srcs[e];
        union { f16x8 v; f16x2 p[4]; } hv;
        hv.v = *(const f16x8*)(P + ((size_t)s << 7) + c0);
        float p = 0.f;
#pragma unroll
        for (int k = 0; k < 4; ++k)
            p = __builtin_amdgcn_fdot2(pk_leaky(hv.p[k] + r2[k]), t2[k], p, false);
        p = dpp_sum16(p);
        float w = __expf(p);
        l_run += w;
#pragma unroll
        for (int j = 0; j < 8; ++j)
            acc[j] = fmaf((float)hv.v[j], w, acc[j]);
    }
    // cross-quarter reduction (quarters processed disjoint edge subsets)
    l_run += __shfl_xor(l_run, 16, 64);
    l_run += __shfl_xor(l_run, 32, 64);
#pragma unroll
    for (int j = 0; j < 8; ++j) {
        acc[j] += __shfl_xor(acc[j], 16, 64);
        acc[j] += __shfl_xor(acc[j], 32, 64);
    }
    float inv = 1.f / l_run;
    int cw = c0 + qd * 2;
    float2 w2;
    w2.x = elu1(acc[qd * 2]     * inv + bias[cw]);
    w2.y = elu1(acc[qd * 2 + 1] * inv + bias[cw + 1]);
    *(float2*)(out + (size_t)n * 128 + cw) = w2;
}

// -------------------- fused pool (segmented) + MLP -------------------------
__global__ __launch_bounds__(256) void poolmlp_kernel(
    const float* __restrict__ h3, const int* __restrict__ gstart,
    const float* __restrict__ W1, const float* __restrict__ b1,
    const float* __restrict__ W2, const float* __restrict__ b2,
    float* __restrict__ out) {
    __shared__ float red[256];
    __shared__ float pr[128];
    __shared__ float2 mred[128];
    int g = blockIdx.x;
    int t = threadIdx.x;
    int c = t & 127;
    int h = t >> 7;    // 0/1
    int gs = gstart[g], ge = gstart[g + 1];
    float s = 0.f;
    for (int n = gs + h; n < ge; n += 2) s += h3[(size_t)n * 128 + c];
    red[t] = s;
    __syncthreads();
    if (h == 0) {
        float tot = red[c] + red[c + 128];
        float cntf = fmaxf((float)(ge - gs), 1.f);
        pr[c] = tot / cntf;
    }
    __syncthreads();
    if (t < 128) {
        float hh = b1[t];
#pragma unroll 4
        for (int k = 0; k < 128; ++k) hh = fmaf(pr[k], W1[k * 128 + t], hh);
        hh = fmaxf(hh, 0.0f);
        mred[t] = make_float2(hh * W2[t * 2], hh * W2[t * 2 + 1]);
    }
    __syncthreads();
    for (int ss = 64; ss > 0; ss >>= 1) {
        if (t < ss) {
            mred[t].x += mred[t + ss].x;
            mred[t].y += mred[t + ss].y;
        }
        __syncthreads();
    }
    if (t == 0) {
        out[g * 2]     = mred[0].x + b2[0];
        out[g * 2 + 1] = mred[0].y + b2[1];
    }
}

// ------------------------------ launch -------------------------------------
extern "C" void kernel_launch(void* const* d_in, const int* in_sizes, int n_in,
                              void* d_out, int out_size, void* d_ws, size_t ws_size,
                              hipStream_t stream) {
    const float* x     = (const float*)d_in[0];
    const int*   esrc  = (const int*)d_in[1];
    const int*   edst  = (const int*)d_in[2];
    const int*   batch = (const int*)d_in[3];
    const float* Wl1   = (const float*)d_in[4];
    const float* Wr1   = (const float*)d_in[5];
    const float* bl1   = (const float*)d_in[6];
    const float* br1   = (const float*)d_in[7];
    const float* att1  = (const float*)d_in[8];
    const float* bias1 = (const float*)d_in[9];
    const float* Wl2   = (const float*)d_in[10];
    const float* Wr2   = (const float*)d_in[11];
    const float* bl2   = (const float*)d_in[12];
    const float* br2   = (const float*)d_in[13];
    const float* att2  = (const float*)d_in[14];
    const float* bias2 = (const float*)d_in[15];
    const float* Wl3   = (const float*)d_in[16];
    const float* Wr3   = (const float*)d_in[17];
    const float* bl3   = (const float*)d_in[18];
    const float* br3   = (const float*)d_in[19];
    const float* att3  = (const float*)d_in[20];
    const float* bias3 = (const float*)d_in[21];
    const float* Wm1   = (const float*)d_in[22];
    const float* bm1   = (const float*)d_in[23];
    const float* Wm2   = (const float*)d_in[24];
    const float* bm2   = (const float*)d_in[25];

    int N  = in_sizes[0] / 128;        // 20000
    int E  = in_sizes[1];              // 320000
    int ET = E + N;
    int B  = out_size / 2;             // 64 graphs
    const int Mp = 160 * 128;          // 20480 rows (8-tile-aligned for swizzle)
    int nch = (N + 255) / 256;         // scan chunks

    // --- workspace carve-up ---
    char* ws = (char*)d_ws;
    size_t off = 0;
    auto alloc = [&](size_t bytes) -> void* {
        void* p = ws + off;
        off += (bytes + 255) & ~(size_t)255;
        return p;
    };
    _Float16* P    = (_Float16*)alloc((size_t)Mp * 512 * 2);  // xl gather table
    _Float16* Q    = (_Float16*)alloc((size_t)Mp * 512 * 2);  // xr (fp16)
    _Float16* A1   = (_Float16*)alloc((size_t)Mp * 128 * 2);  // fp16(x)
    _Float16* Hb   = (_Float16*)alloc((size_t)Mp * 512 * 2);  // edge out / next A
    _Float16* Wth1 = (_Float16*)alloc((size_t)1024 * 128 * 2);
    _Float16* Wtl1 = (_Float16*)alloc((size_t)1024 * 128 * 2);
    _Float16* Wth2 = (_Float16*)alloc((size_t)1024 * 512 * 2);
    _Float16* Wtl2 = (_Float16*)alloc((size_t)1024 * 512 * 2);
    _Float16* Wth3 = (_Float16*)alloc((size_t)256 * 512 * 2);
    _Float16* Wtl3 = (_Float16*)alloc((size_t)256 * 512 * 2);
    float*    R3   = (float*)alloc((size_t)Mp * 128 * 4);     // layer-3 edge out
    int*    cnt      = (int*)alloc((size_t)N * 4);
    int*    psum     = (int*)alloc((size_t)(nch + 1) * 4);
    int*    rowstart = (int*)alloc((size_t)(N + 1) * 4);
    int*    cursor   = (int*)alloc((size_t)N * 4);
    int*    csr_src  = (int*)alloc((size_t)ET * 4 + 64);      // +pad for prefetch over-read
    int*    gstart   = (int*)alloc((size_t)(B + 1) * 4);
    (void)ws_size;

    // --- zero cnt (memset, no launch) ---
    hipMemsetAsync(cnt, 0, (size_t)N * 4, stream);

    // --- fused prep (convWT x3, convA, boundary, degree count) ---
    int cblocks = (ET + 255) / 256;
    prep_kernel<<<3407 + cblocks, 256, 0, stream>>>(
        Wl1, Wr1, Wth1, Wtl1, Wl2, Wr2, Wth2, Wtl2, Wl3, Wr3, Wth3, Wtl3,
        x, A1, N * 128, Mp * 128, batch, gstart, N, B, edst, cnt, E);

    // --- CSR build (3-phase scan) + scatter ---
    scan1_kernel<<<nch, 256, 0, stream>>>(cnt, psum, N);
    scan2_kernel<<<1, 128, 0, stream>>>(psum, nch);
    scan3_kernel<<<nch, 256, 0, stream>>>(cnt, psum, rowstart, cursor, N);
    scatter_kernel<<<cblocks, 256, 0, stream>>>(esrc, edst, cursor, csr_src, E, N);

    int eblocks = (N + 1) / 2;

    // --- layer 1: fused N=1024 GEMM -> P | Q (fp16) ---
    gemm_f16_kernel<<<160 * 8, 256, 0, stream>>>(A1, Wth1, Wtl1, bl1, br1, 512, P, Q, 128, 8);
    gat_edge4_kernel<<<eblocks, 128, 0, stream>>>(P, Q, att1, bias1, rowstart, csr_src, Hb, N);

    // --- layer 2 ---
    gemm_f16_kernel<<<160 * 8, 256, 0, stream>>>(Hb, Wth2, Wtl2, bl2, br2, 512, P, Q, 512, 8);
    gat_edge4_kernel<<<eblocks, 128, 0, stream>>>(P, Q, att2, bias2, rowstart, csr_src, Hb, N);

    // --- layer 3 (1 head): fused N=256 GEMM -> P | Q (fp16), ld=128 ---
    gemm_f16_kernel<<<160 * 2, 256, 0, stream>>>(Hb, Wth3, Wtl3, bl3, br3, 128, P, Q, 512, 2);
    gat_edge1_kernel<<<eblocks, 128, 0, stream>>>(P, Q, att3, bias3, rowstart, csr_src, R3, N);

    // --- fused pool + MLP ---
    poolmlp_kernel<<<B, 256, 0, stream>>>(R3, gstart, Wm1, bm1, Wm2, bm2, (float*)d_out);
}